// Round 5
// baseline (283.050 us; speedup 1.0000x reference)
//
#include <hip/hip_runtime.h>

#define N_NODES 100000
#define N_EDGES 640000
#define D 128
#define NB ((N_NODES + 1023) / 1024)   // 98 scan blocks
#define BKT_C 16                        // bucket capacity: 16 ints = one 64B line
#define OVF_CAP 32768

typedef short v8s __attribute__((ext_vector_type(8)));
typedef float v4f __attribute__((ext_vector_type(4)));

__device__ __forceinline__ unsigned short f2bf(float x) {
    unsigned int u = __builtin_bit_cast(unsigned int, x);
    u += 0x7fffu + ((u >> 16) & 1u);   // RNE
    return (unsigned short)(u >> 16);
}
__device__ __forceinline__ float bf2f(unsigned int hi) {
    return __builtin_bit_cast(float, hi << 16);
}

// ---------------------------------------------------------------------------
// k_zero: zero pk[N] (deg_src lo16 | cnt_dst hi16) + ovf_cnt.
// KEEP AS A KERNEL (not hipMemsetAsync): stores write-allocate pk near the
// coherence point so k_pre's atomics hit warm lines (rounds 1-2 lesson).
// ---------------------------------------------------------------------------
__global__ __launch_bounds__(256) void k_zero(int4* __restrict__ pk4,
                                              int* __restrict__ ovf_cnt) {
    int i = blockIdx.x * blockDim.x + threadIdx.x;
    if (i < N_NODES / 4) pk4[i] = make_int4(0, 0, 0, 0);
    if (i == 0) *ovf_cnt = 0;
}

// ---------------------------------------------------------------------------
// k_pre: EXACT round-3 body (best measured ~74us). featsh bf16 pack into
// SECOND 256B of each 512B d_out row; weights -> Bcat bf16; bias=bm+bs;
// first 640K threads count degrees and (path A) scatter src into per-dst
// 16-entry INT buckets. Round-4 lesson: scattered-atomic fabric cost scales
// with op count, not element size — do not add streams (hibits) or shrink
// elements (ushort).
// ---------------------------------------------------------------------------
__global__ __launch_bounds__(256) void k_pre(const float* __restrict__ feats,
                                             const float* __restrict__ Wm,
                                             const float* __restrict__ Ws,
                                             const float* __restrict__ bmsg,
                                             const float* __restrict__ bskip,
                                             const int* __restrict__ src,
                                             const int* __restrict__ dst,
                                             unsigned int* __restrict__ pk,
                                             unsigned short* __restrict__ Bcat,
                                             float* __restrict__ bias,
                                             char* __restrict__ outb,
                                             int* __restrict__ bucket,
                                             int* __restrict__ ovf_cnt,
                                             int2* __restrict__ ovf) {
    int i = blockIdx.x * blockDim.x + threadIdx.x;
    if (i < D * D) {
        int j = i >> 7;
        int k = i & 127;
        Bcat[j * 256 + k]       = f2bf(Wm[i]);
        Bcat[j * 256 + 128 + k] = f2bf(Ws[i]);
    }
    if (i < D) bias[i] = bmsg[i] + bskip[i];
    if (i < N_EDGES) {
        int s = src[i];
        int d = dst[i];
        atomicAdd(&pk[s], 1u);
        unsigned int old = atomicAdd(&pk[d], 0x10000u);
        if (bucket) {
            unsigned int p = old >> 16;
            if (p < BKT_C) {
                bucket[d * BKT_C + (int)p] = s;
            } else {
                int q = atomicAdd(ovf_cnt, 1);
                if (q < OVF_CAP) ovf[q] = make_int2(d, s);
            }
        }
    }
    int g = i * 8;
    int row = g >> 7;
    int col = g & 127;
    if (row < N_NODES) {
        const float4* sp = (const float4*)(feats + g);
        float4 x = sp[0], y = sp[1];
        uint4 p;
        p.x = (unsigned)f2bf(x.x) | ((unsigned)f2bf(x.y) << 16);
        p.y = (unsigned)f2bf(x.z) | ((unsigned)f2bf(x.w) << 16);
        p.z = (unsigned)f2bf(y.x) | ((unsigned)f2bf(y.y) << 16);
        p.w = (unsigned)f2bf(y.z) | ((unsigned)f2bf(y.w) << 16);
        *(uint4*)(outb + (size_t)row * 512 + 256 + col * 2) = p;
    }
}

// ---------------------------------------------------------------------------
// k_fused (Path A): agg + gemm in one kernel. Block = 256 thr / 4 waves /
// 128 rows. Wave w aggregates nodes n0+w*32+{0..31} into LDS (bf16, 264B
// row stride: 66 dwords -> ~4-way worst-case bank aliasing, acceptable),
// then runs its own 32-row MFMA tile reading aggh from LDS, featsh (OWN
// rows) from d_out, and B from global (Bcat 64KB, L2-resident). No
// __syncthreads anywhere: waves are fully independent.
// RACE NOTE: gathers read the ORIGINAL fp32 feats (read-only input), never
// d_out — so C-writes by other blocks can't corrupt gathers. featsh reads
// are own-rows only, within-wave before the C-write.
// ---------------------------------------------------------------------------
__global__ __launch_bounds__(256) void k_fused(const float* __restrict__ feats,
                                               const unsigned int* __restrict__ pk,
                                               const int* __restrict__ bucket,
                                               const int* __restrict__ ovf_cnt,
                                               const int2* __restrict__ ovf,
                                               const unsigned short* __restrict__ Bcat,
                                               const float* __restrict__ bias,
                                               float* __restrict__ outf) {
    __shared__ unsigned short aggh[128][132];   // 264B stride, 33.8KB total
    int tid = threadIdx.x;
    int lane = tid & 63;
    int w = tid >> 6;
    int n0 = blockIdx.x * 128;
    int grp = lane >> 4;
    int sub = lane & 15;

    // ---------------- agg phase: 32 nodes per wave ----------------
#pragma unroll 2
    for (int j = 0; j < 32; ++j) {
        int wid = n0 + w * 32 + j;
        int widc = wid < N_NODES ? wid : N_NODES - 1;
        unsigned int pkn = pk[widc];
        int cnt = (int)(pkn >> 16);
        int m = cnt < BKT_C ? cnt : BKT_C;
        const int* bk = bucket + widc * BKT_C;

        int4 bq = *(const int4*)(bk + grp * 4);
        int e0 = grp * 4;
        bool a0 = e0 < m, a1 = e0 + 1 < m, a2 = e0 + 2 < m, a3 = e0 + 3 < m;
        int sA = a0 ? bq.x : 0; float gA = a0 ? 1.0f : 0.0f;
        int sB = a1 ? bq.y : 0; float gB = a1 ? 1.0f : 0.0f;
        int sC = a2 ? bq.z : 0; float gC = a2 ? 1.0f : 0.0f;
        int sD = a3 ? bq.w : 0; float gD = a3 ? 1.0f : 0.0f;

        // 4 degree loads + 8 row loads (fp32, 32B/lane/edge) in flight
        unsigned int pA = pk[sA];
        unsigned int pB = pk[sB];
        unsigned int pC = pk[sC];
        unsigned int pD = pk[sD];
        const float4* rA = (const float4*)(feats + (size_t)sA * 128 + sub * 8);
        const float4* rB = (const float4*)(feats + (size_t)sB * 128 + sub * 8);
        const float4* rC = (const float4*)(feats + (size_t)sC * 128 + sub * 8);
        const float4* rD = (const float4*)(feats + (size_t)sD * 128 + sub * 8);
        float4 uA = rA[0], vA = rA[1];
        float4 uB = rB[0], vB = rB[1];
        float4 uC = rC[0], vC = rC[1];
        float4 uD = rD[0], vD = rD[1];

        float scA = gA * rsqrtf(fmaxf((float)(pA & 0xffffu), 1.0f));
        float scB = gB * rsqrtf(fmaxf((float)(pB & 0xffffu), 1.0f));
        float scC = gC * rsqrtf(fmaxf((float)(pC & 0xffffu), 1.0f));
        float scD = gD * rsqrtf(fmaxf((float)(pD & 0xffffu), 1.0f));

        float acc[8];
#pragma unroll
        for (int i = 0; i < 8; i++) acc[i] = 0.f;
        acc[0] += uA.x * scA; acc[1] += uA.y * scA; acc[2] += uA.z * scA; acc[3] += uA.w * scA;
        acc[4] += vA.x * scA; acc[5] += vA.y * scA; acc[6] += vA.z * scA; acc[7] += vA.w * scA;
        acc[0] += uB.x * scB; acc[1] += uB.y * scB; acc[2] += uB.z * scB; acc[3] += uB.w * scB;
        acc[4] += vB.x * scB; acc[5] += vB.y * scB; acc[6] += vB.z * scB; acc[7] += vB.w * scB;
        acc[0] += uC.x * scC; acc[1] += uC.y * scC; acc[2] += uC.z * scC; acc[3] += uC.w * scC;
        acc[4] += vC.x * scC; acc[5] += vC.y * scC; acc[6] += vC.z * scC; acc[7] += vC.w * scC;
        acc[0] += uD.x * scD; acc[1] += uD.y * scD; acc[2] += uD.z * scD; acc[3] += uD.w * scD;
        acc[4] += vD.x * scD; acc[5] += vD.y * scD; acc[6] += vD.z * scD; acc[7] += vD.w * scD;

        if (cnt > BKT_C) {   // rare: scan tiny overflow list (fp32 gather)
            int no = *ovf_cnt;
            if (no > OVF_CAP) no = OVF_CAP;
            for (int i = grp; i < no; i += 4) {
                int2 p = ovf[i];
                if (p.x == widc) {
                    float sc = rsqrtf((float)(pk[p.y] & 0xffffu));
                    const float4* rp = (const float4*)(feats + (size_t)p.y * 128 + sub * 8);
                    float4 u = rp[0], v = rp[1];
                    acc[0] += u.x * sc; acc[1] += u.y * sc; acc[2] += u.z * sc; acc[3] += u.w * sc;
                    acc[4] += v.x * sc; acc[5] += v.y * sc; acc[6] += v.z * sc; acc[7] += v.w * sc;
                }
            }
        }

#pragma unroll
        for (int i = 0; i < 8; i++) {
            acc[i] += __shfl_xor(acc[i], 16);
            acc[i] += __shfl_xor(acc[i], 32);
        }
        if (grp == 0) {
            int dsrc = (int)(pkn & 0xffffu);
            float scn = (dsrc > 0) ? rsqrtf((float)dsrc) : 0.0f;
            uint4 p;
            p.x = (unsigned)f2bf(acc[0] * scn) | ((unsigned)f2bf(acc[1] * scn) << 16);
            p.y = (unsigned)f2bf(acc[2] * scn) | ((unsigned)f2bf(acc[3] * scn) << 16);
            p.z = (unsigned)f2bf(acc[4] * scn) | ((unsigned)f2bf(acc[5] * scn) << 16);
            p.w = (unsigned)f2bf(acc[6] * scn) | ((unsigned)f2bf(acc[7] * scn) << 16);
            *(uint4*)(&aggh[w * 32 + j][sub * 8]) = p;
        }
    }

    // ---------------- gemm phase: wave-private 32-row tile ----------------
    const char* Ab = (const char*)outf;
    int q = grp;
    int lr = sub;
    int r0 = n0 + w * 32 + lr;      int r0c = r0 < N_NODES ? r0 : N_NODES - 1;
    int r1 = r0 + 16;               int r1c = r1 < N_NODES ? r1 : N_NODES - 1;
    const char* a0p = Ab + (size_t)r0c * 512 + 256 + q * 16;   // featsh half
    const char* a1p = Ab + (size_t)r1c * 512 + 256 + q * 16;

    v4f acc2[2][8];
#pragma unroll
    for (int mt = 0; mt < 2; mt++)
#pragma unroll
        for (int t = 0; t < 8; t++) acc2[mt][t] = (v4f){0.f, 0.f, 0.f, 0.f};

#pragma unroll
    for (int kk = 0; kk < 8; kk++) {
        v8s a0, a1;
        if (kk < 4) {   // aggh half from LDS
            a0 = *(const v8s*)(&aggh[w * 32 + lr][q * 8 + kk * 32]);
            a1 = *(const v8s*)(&aggh[w * 32 + 16 + lr][q * 8 + kk * 32]);
        } else {        // featsh half from global (own rows)
            a0 = *(const v8s*)(a0p + (kk - 4) * 64);
            a1 = *(const v8s*)(a1p + (kk - 4) * 64);
        }
#pragma unroll
        for (int t = 0; t < 8; t++) {
            v8s b = *(const v8s*)(Bcat + (t * 16 + lr) * 256 + kk * 32 + q * 8);
            acc2[0][t] = __builtin_amdgcn_mfma_f32_16x16x32_bf16(a0, b, acc2[0][t], 0, 0, 0);
            acc2[1][t] = __builtin_amdgcn_mfma_f32_16x16x32_bf16(a1, b, acc2[1][t], 0, 0, 0);
        }
    }

#pragma unroll
    for (int t = 0; t < 8; t++) {
        float bv = bias[t * 16 + lr];
#pragma unroll
        for (int mt = 0; mt < 2; mt++) {
            int rowb = n0 + w * 32 + mt * 16 + q * 4;
#pragma unroll
            for (int r = 0; r < 4; r++) {
                int row = rowb + r;
                if (row < N_NODES)
                    outf[(size_t)row * 128 + t * 16 + lr] = acc2[mt][t][r] + bv;
            }
        }
    }
}

// ---------------------------------------------------------------------------
// Path B fallback: exclusive scan of cnt_dst (pk hi16) -> rowptr, then fill.
// ---------------------------------------------------------------------------
__global__ __launch_bounds__(256) void k_scan1(const unsigned int* __restrict__ pk,
                                               int* __restrict__ rowptr,
                                               int* __restrict__ bsums) {
    __shared__ int sd[256];
    int t = threadIdx.x;
    int i0 = blockIdx.x * 1024 + t * 4;
    int v[4];
    int s = 0;
#pragma unroll
    for (int q = 0; q < 4; q++) {
        int i = i0 + q;
        v[q] = (i < N_NODES) ? (int)(pk[i] >> 16) : 0;
        s += v[q];
    }
    sd[t] = s;
    __syncthreads();
    for (int off = 1; off < 256; off <<= 1) {
        int y = (t >= off) ? sd[t - off] : 0;
        __syncthreads();
        sd[t] += y;
        __syncthreads();
    }
    int run = sd[t] - s;
    if (t == 255) bsums[blockIdx.x] = sd[255];
#pragma unroll
    for (int q = 0; q < 4; q++) {
        int i = i0 + q;
        if (i < N_NODES) rowptr[i] = run;
        run += v[q];
    }
}

__global__ __launch_bounds__(128) void k_scan2(int* __restrict__ bsums) {
    __shared__ int sd[128];
    int t = threadIdx.x;
    int v = (t < NB) ? bsums[t] : 0;
    sd[t] = v;
    __syncthreads();
    for (int off = 1; off < 128; off <<= 1) {
        int y = (t >= off) ? sd[t - off] : 0;
        __syncthreads();
        sd[t] += y;
        __syncthreads();
    }
    if (t < NB) bsums[t] = sd[t] - v;
}

__global__ __launch_bounds__(256) void k_scan3(const int* __restrict__ bsums,
                                               int* __restrict__ rowptr) {
    int add = bsums[blockIdx.x];
    int i0 = blockIdx.x * 1024 + threadIdx.x * 4;
#pragma unroll
    for (int q = 0; q < 4; q++) {
        int i = i0 + q;
        if (i < N_NODES) rowptr[i] += add;
    }
}

__global__ __launch_bounds__(256) void k_fill(const int* __restrict__ src,
                                              const int* __restrict__ dst,
                                              int* __restrict__ rowptr,
                                              int* __restrict__ csr_src) {
    int e = blockIdx.x * blockDim.x + threadIdx.x;
    if (e < N_EDGES) {
        int p = atomicAdd(&rowptr[dst[e]], 1);
        csr_src[p] = src[e];
    }
}

// ---------------------------------------------------------------------------
// Path B agg helpers (bf16 featsh gather from d_out rows — safe in Path B
// because agg and gemm are separate kernels there).
// ---------------------------------------------------------------------------
__device__ __forceinline__ void agg_edge(const char* outb,
                                         const unsigned int* pk,
                                         int s, int sub, float* acc) {
    float sc = rsqrtf((float)(pk[s] & 0xffffu));
    uint4 v = *(const uint4*)(outb + (size_t)s * 512 + 256 + sub * 16);
    acc[0] += bf2f(v.x & 0xffffu) * sc;
    acc[1] += bf2f(v.x >> 16) * sc;
    acc[2] += bf2f(v.y & 0xffffu) * sc;
    acc[3] += bf2f(v.y >> 16) * sc;
    acc[4] += bf2f(v.z & 0xffffu) * sc;
    acc[5] += bf2f(v.z >> 16) * sc;
    acc[6] += bf2f(v.w & 0xffffu) * sc;
    acc[7] += bf2f(v.w >> 16) * sc;
}

__device__ __forceinline__ void agg_finish(char* outb, int wid,
                                           unsigned int pkn, int grp, int sub,
                                           float* acc) {
#pragma unroll
    for (int i = 0; i < 8; i++) {
        acc[i] += __shfl_xor(acc[i], 16);
        acc[i] += __shfl_xor(acc[i], 32);
    }
    if (grp == 0) {
        int dsrc = (int)(pkn & 0xffffu);
        float scn = (dsrc > 0) ? rsqrtf((float)dsrc) : 0.0f;
        uint4 p;
        p.x = (unsigned)f2bf(acc[0] * scn) | ((unsigned)f2bf(acc[1] * scn) << 16);
        p.y = (unsigned)f2bf(acc[2] * scn) | ((unsigned)f2bf(acc[3] * scn) << 16);
        p.z = (unsigned)f2bf(acc[4] * scn) | ((unsigned)f2bf(acc[5] * scn) << 16);
        p.w = (unsigned)f2bf(acc[6] * scn) | ((unsigned)f2bf(acc[7] * scn) << 16);
        *(uint4*)(outb + (size_t)wid * 512 + sub * 16) = p;
    }
}

// Path B: end-pointer CSR aggregation
__global__ __launch_bounds__(256) void k_agg_csr(char* __restrict__ outb,
                                                 const unsigned int* __restrict__ pk,
                                                 const int* __restrict__ rowptr,
                                                 const int* __restrict__ csr_src) {
    int wid = (int)((blockIdx.x * (unsigned)blockDim.x + threadIdx.x) >> 6);
    int lane = threadIdx.x & 63;
    if (wid >= N_NODES) return;
    int grp = lane >> 4;
    int sub = lane & 15;
    int start = (wid == 0) ? 0 : rowptr[wid - 1];
    int end = rowptr[wid];
    float acc[8];
#pragma unroll
    for (int i = 0; i < 8; i++) acc[i] = 0.f;
    for (int base = start; base < end; base += 4) {
        int e = base + grp;
        if (e < end) agg_edge(outb, pk, csr_src[e], sub, acc);
    }
    agg_finish(outb, wid, pk[wid], grp, sub, acc);
}

// ---------------------------------------------------------------------------
// k_gemm (Path B only): out[n,:] = Arow[n] @ Bcat^T + bias, MFMA 16x16x32
// bf16, K=256. Arow = packed [aggh|featsh] bf16 rows in d_out.
// ---------------------------------------------------------------------------
__global__ __launch_bounds__(256) void k_gemm(const unsigned short* __restrict__ Bcat,
                                              const float* __restrict__ bias,
                                              float* __restrict__ outf) {
    __shared__ unsigned short Bl[128][264];
    const char* Ab = (const char*)outf;
    int tid = threadIdx.x;
    int lane = tid & 63;
    int w = tid >> 6;
    int n0 = blockIdx.x * 128;

    for (int i = tid; i < 128 * 32; i += 256) {
        int r = i >> 5, c = i & 31;
        *(uint4*)(&Bl[r][c * 8]) = *(const uint4*)(Bcat + r * 256 + c * 8);
    }
    __syncthreads();

    int q = lane >> 4;
    int lr = lane & 15;

    int r0 = n0 + w * 32 + lr;      if (r0 > N_NODES - 1) r0 = N_NODES - 1;
    int r1 = n0 + w * 32 + 16 + lr; if (r1 > N_NODES - 1) r1 = N_NODES - 1;
    const char* a0p = Ab + (size_t)r0 * 512 + q * 16;
    const char* a1p = Ab + (size_t)r1 * 512 + q * 16;

    v4f acc[2][8];
#pragma unroll
    for (int mt = 0; mt < 2; mt++)
#pragma unroll
        for (int t = 0; t < 8; t++) acc[mt][t] = (v4f){0.f, 0.f, 0.f, 0.f};

#pragma unroll
    for (int kk = 0; kk < 8; kk++) {
        v8s a0 = *(const v8s*)(a0p + kk * 64);
        v8s a1 = *(const v8s*)(a1p + kk * 64);
#pragma unroll
        for (int t = 0; t < 8; t++) {
            v8s b = *(const v8s*)(&Bl[t * 16 + lr][kk * 32 + q * 8]);
            acc[0][t] = __builtin_amdgcn_mfma_f32_16x16x32_bf16(a0, b, acc[0][t], 0, 0, 0);
            acc[1][t] = __builtin_amdgcn_mfma_f32_16x16x32_bf16(a1, b, acc[1][t], 0, 0, 0);
        }
    }

#pragma unroll
    for (int t = 0; t < 8; t++) {
        float bv = bias[t * 16 + lr];
#pragma unroll
        for (int mt = 0; mt < 2; mt++) {
            int rowb = n0 + w * 32 + mt * 16 + q * 4;
#pragma unroll
            for (int r = 0; r < 4; r++) {
                int row = rowb + r;
                if (row < N_NODES)
                    outf[(size_t)row * 128 + t * 16 + lr] = acc[mt][t][r] + bv;
            }
        }
    }
}

// ---------------------------------------------------------------------------
extern "C" void kernel_launch(void* const* d_in, const int* in_sizes, int n_in,
                              void* d_out, int out_size, void* d_ws, size_t ws_size,
                              hipStream_t stream) {
    const float* feats = (const float*)d_in[0];
    const int*   src   = (const int*)d_in[1];
    const int*   dst   = (const int*)d_in[2];
    const float* Wskip = (const float*)d_in[3];
    const float* bskip = (const float*)d_in[4];
    const float* Wmsg  = (const float*)d_in[5];
    const float* bmsg  = (const float*)d_in[6];

    char* w = (char*)d_ws;

    // Path A layout (single-pass bucketing), needs 7,128,320 B:
    //   [0,      400000)  uint pk[N]
    //   [400000, 400128)  int  ovf_cnt (+pad)
    //   [400128, 465664)  ushort Bcat[128*256]
    //   [465664, 466176)  float bias[128]
    //   [466176,6866176)  int  bucket[N*16]
    //   [6866176,7128320) int2 ovf[32768]
    // Path B layout (count+scan+fill), needs 3,426,688 B:
    //   [0,      400000)  uint pk[N]
    //   [400000, 800128)  int  rowptr[N+1] (+pad)
    //   [800128, 800640)  int  bsums[128]
    //   [800640, 866176)  ushort Bcat
    //   [866176, 866688)  float bias
    //   [866688,3426688)  int  csr_src[E]
    bool pathA = ws_size >= (size_t)7128320;

    if (pathA) {
        unsigned int*   pk      = (unsigned int*)w;
        int*            ovf_cnt = (int*)(w + 400000);
        unsigned short* Bcat    = (unsigned short*)(w + 400128);
        float*          bias    = (float*)(w + 465664);
        int*            bucket  = (int*)(w + 466176);
        int2*           ovf     = (int2*)(w + 6866176);

        hipLaunchKernelGGL(k_zero, dim3((N_NODES / 4 + 255) / 256), dim3(256), 0,
                           stream, (int4*)pk, ovf_cnt);
        hipLaunchKernelGGL(k_pre, dim3((N_NODES * (D / 8) + 255) / 256), dim3(256),
                           0, stream, feats, Wmsg, Wskip, bmsg, bskip, src, dst, pk,
                           Bcat, bias, (char*)d_out, bucket, ovf_cnt, ovf);
        hipLaunchKernelGGL(k_fused, dim3((N_NODES + 127) / 128), dim3(256), 0,
                           stream, feats, pk, bucket, ovf_cnt, ovf, Bcat, bias,
                           (float*)d_out);
    } else {
        unsigned int*   pk      = (unsigned int*)w;
        int*            rowptr  = (int*)(w + 400000);
        int*            bsums   = (int*)(w + 800128);
        unsigned short* Bcat    = (unsigned short*)(w + 800640);
        float*          bias    = (float*)(w + 866176);
        int*            csr_src = (int*)(w + 866688);

        hipLaunchKernelGGL(k_zero, dim3((N_NODES / 4 + 255) / 256), dim3(256), 0,
                           stream, (int4*)pk, (int*)(w + 400000) /*unused slot*/);
        hipLaunchKernelGGL(k_pre, dim3((N_NODES * (D / 8) + 255) / 256), dim3(256),
                           0, stream, feats, Wmsg, Wskip, bmsg, bskip, src, dst, pk,
                           Bcat, bias, (char*)d_out, (int*)nullptr, (int*)nullptr,
                           (int2*)nullptr);
        hipLaunchKernelGGL(k_scan1, dim3(NB), dim3(256), 0, stream, pk, rowptr,
                           bsums);
        hipLaunchKernelGGL(k_scan2, dim3(1), dim3(128), 0, stream, bsums);
        hipLaunchKernelGGL(k_scan3, dim3(NB), dim3(256), 0, stream, bsums, rowptr);
        hipLaunchKernelGGL(k_fill, dim3((N_EDGES + 255) / 256), dim3(256), 0, stream,
                           src, dst, rowptr, csr_src);
        hipLaunchKernelGGL(k_agg_csr, dim3((N_NODES * 64 + 255) / 256), dim3(256), 0,
                           stream, (char*)d_out, pk, rowptr, csr_src);
        hipLaunchKernelGGL(k_gemm, dim3((N_NODES + 127) / 128), dim3(256), 0, stream,
                           Bcat, bias, (float*)d_out);
    }
}

// Round 6
// 269.971 us; speedup vs baseline: 1.0484x; 1.0484x over previous
//
#include <hip/hip_runtime.h>

#define N_NODES 100000
#define N_EDGES 640000
#define D 128
#define NB ((N_NODES + 1023) / 1024)   // 98 scan blocks
#define BKT_C 16                        // bucket capacity: 16 ints = one 64B line
#define OVF_CAP 32768

typedef short v8s __attribute__((ext_vector_type(8)));
typedef float v4f __attribute__((ext_vector_type(4)));

__device__ __forceinline__ unsigned short f2bf(float x) {
    unsigned int u = __builtin_bit_cast(unsigned int, x);
    u += 0x7fffu + ((u >> 16) & 1u);   // RNE
    return (unsigned short)(u >> 16);
}
__device__ __forceinline__ float bf2f(unsigned int hi) {
    return __builtin_bit_cast(float, hi << 16);
}

// ---------------------------------------------------------------------------
// k_zero: zero pk[N] (deg_src lo16 | cnt_dst hi16) + ovf_cnt.
// KEEP AS A KERNEL (not hipMemsetAsync): stores write-allocate pk near the
// coherence point so k_pre's atomics hit warm lines (rounds 1-2 lesson).
// ---------------------------------------------------------------------------
__global__ __launch_bounds__(256) void k_zero(int4* __restrict__ pk4,
                                              int* __restrict__ ovf_cnt) {
    int i = blockIdx.x * blockDim.x + threadIdx.x;
    if (i < N_NODES / 4) pk4[i] = make_int4(0, 0, 0, 0);
    if (i == 0) *ovf_cnt = 0;
}

// ---------------------------------------------------------------------------
// k_pre: featsh bf16 pack to fsbase + row*fs_stride (Path A/B: d_out+256,
// stride 512 interleaved; Path C: compact ws array, stride 256); weights ->
// Bcat bf16; bias=bm+bs; first 640K threads count degrees and scatter src
// into per-dst 16-entry INT buckets. Round-4 lesson: scattered-atomic fabric
// cost scales with op count, not element size — no extra streams.
// ---------------------------------------------------------------------------
__global__ __launch_bounds__(256) void k_pre(const float* __restrict__ feats,
                                             const float* __restrict__ Wm,
                                             const float* __restrict__ Ws,
                                             const float* __restrict__ bmsg,
                                             const float* __restrict__ bskip,
                                             const int* __restrict__ src,
                                             const int* __restrict__ dst,
                                             unsigned int* __restrict__ pk,
                                             unsigned short* __restrict__ Bcat,
                                             float* __restrict__ bias,
                                             char* __restrict__ fsbase,
                                             int fs_stride,
                                             int* __restrict__ bucket,
                                             int* __restrict__ ovf_cnt,
                                             int2* __restrict__ ovf) {
    int i = blockIdx.x * blockDim.x + threadIdx.x;
    if (i < D * D) {
        int j = i >> 7;
        int k = i & 127;
        Bcat[j * 256 + k]       = f2bf(Wm[i]);
        Bcat[j * 256 + 128 + k] = f2bf(Ws[i]);
    }
    if (i < D) bias[i] = bmsg[i] + bskip[i];
    if (i < N_EDGES) {
        int s = src[i];
        int d = dst[i];
        atomicAdd(&pk[s], 1u);
        unsigned int old = atomicAdd(&pk[d], 0x10000u);
        if (bucket) {
            unsigned int p = old >> 16;
            if (p < BKT_C) {
                bucket[d * BKT_C + (int)p] = s;
            } else {
                int q = atomicAdd(ovf_cnt, 1);
                if (q < OVF_CAP) ovf[q] = make_int2(d, s);
            }
        }
    }
    int g = i * 8;
    int row = g >> 7;
    int col = g & 127;
    if (row < N_NODES) {
        const float4* sp = (const float4*)(feats + g);
        float4 x = sp[0], y = sp[1];
        uint4 p;
        p.x = (unsigned)f2bf(x.x) | ((unsigned)f2bf(x.y) << 16);
        p.y = (unsigned)f2bf(x.z) | ((unsigned)f2bf(x.w) << 16);
        p.z = (unsigned)f2bf(y.x) | ((unsigned)f2bf(y.y) << 16);
        p.w = (unsigned)f2bf(y.z) | ((unsigned)f2bf(y.w) << 16);
        *(uint4*)(fsbase + (size_t)row * fs_stride + col * 2) = p;
    }
}

// ---------------------------------------------------------------------------
// k_fused2 (Path C only): agg + gemm in one kernel, race-free because featsh
// lives in the WORKSPACE (d_out is write-only). Block = 256 thr / 4 waves /
// 128 rows; wave w aggregates its 32 nodes into LDS (bf16 gather, 16B/lane
// per edge — half of round-5's fp32 gather, which was the measured 170MB
// FETCH regression), then runs its own 32-row MFMA tile: aggh from LDS,
// featsh own rows from ws, B from global Bcat (64KB, L2-resident). No
// __syncthreads: waves independent, early finishers' MFMA overlaps others'
// gathers (m114 co-scheduling).
// ---------------------------------------------------------------------------
__global__ __launch_bounds__(256) void k_fused2(const char* __restrict__ featsh,
                                                const unsigned int* __restrict__ pk,
                                                const int* __restrict__ bucket,
                                                const int* __restrict__ ovf_cnt,
                                                const int2* __restrict__ ovf,
                                                const unsigned short* __restrict__ Bcat,
                                                const float* __restrict__ bias,
                                                float* __restrict__ outf) {
    __shared__ unsigned short aggh[128][132];   // 264B stride, 33.8KB
    int tid = threadIdx.x;
    int lane = tid & 63;
    int w = tid >> 6;
    int n0 = blockIdx.x * 128;
    int grp = lane >> 4;
    int sub = lane & 15;

    // ---------------- agg phase: 32 nodes per wave ----------------
#pragma unroll 2
    for (int j = 0; j < 32; ++j) {
        int wid = n0 + w * 32 + j;
        int widc = wid < N_NODES ? wid : N_NODES - 1;
        unsigned int pkn = pk[widc];
        int cnt = (int)(pkn >> 16);
        int m = cnt < BKT_C ? cnt : BKT_C;
        const int* bk = bucket + widc * BKT_C;

        int4 bq = *(const int4*)(bk + grp * 4);
        int e0 = grp * 4;
        bool a0 = e0 < m, a1 = e0 + 1 < m, a2 = e0 + 2 < m, a3 = e0 + 3 < m;
        int sA = a0 ? bq.x : 0; float gA = a0 ? 1.0f : 0.0f;
        int sB = a1 ? bq.y : 0; float gB = a1 ? 1.0f : 0.0f;
        int sC = a2 ? bq.z : 0; float gC = a2 ? 1.0f : 0.0f;
        int sD = a3 ? bq.w : 0; float gD = a3 ? 1.0f : 0.0f;

        // 4 degree loads + 4 bf16 row loads (16B/lane/edge) in flight
        unsigned int pA = pk[sA];
        unsigned int pB = pk[sB];
        unsigned int pC = pk[sC];
        unsigned int pD = pk[sD];
        uint4 vA = *(const uint4*)(featsh + (size_t)sA * 256 + sub * 16);
        uint4 vB = *(const uint4*)(featsh + (size_t)sB * 256 + sub * 16);
        uint4 vC = *(const uint4*)(featsh + (size_t)sC * 256 + sub * 16);
        uint4 vD = *(const uint4*)(featsh + (size_t)sD * 256 + sub * 16);

        float scA = gA * rsqrtf(fmaxf((float)(pA & 0xffffu), 1.0f));
        float scB = gB * rsqrtf(fmaxf((float)(pB & 0xffffu), 1.0f));
        float scC = gC * rsqrtf(fmaxf((float)(pC & 0xffffu), 1.0f));
        float scD = gD * rsqrtf(fmaxf((float)(pD & 0xffffu), 1.0f));

        float acc[8];
#pragma unroll
        for (int i = 0; i < 8; i++) acc[i] = 0.f;
        acc[0] += bf2f(vA.x & 0xffffu) * scA; acc[1] += bf2f(vA.x >> 16) * scA;
        acc[2] += bf2f(vA.y & 0xffffu) * scA; acc[3] += bf2f(vA.y >> 16) * scA;
        acc[4] += bf2f(vA.z & 0xffffu) * scA; acc[5] += bf2f(vA.z >> 16) * scA;
        acc[6] += bf2f(vA.w & 0xffffu) * scA; acc[7] += bf2f(vA.w >> 16) * scA;
        acc[0] += bf2f(vB.x & 0xffffu) * scB; acc[1] += bf2f(vB.x >> 16) * scB;
        acc[2] += bf2f(vB.y & 0xffffu) * scB; acc[3] += bf2f(vB.y >> 16) * scB;
        acc[4] += bf2f(vB.z & 0xffffu) * scB; acc[5] += bf2f(vB.z >> 16) * scB;
        acc[6] += bf2f(vB.w & 0xffffu) * scB; acc[7] += bf2f(vB.w >> 16) * scB;
        acc[0] += bf2f(vC.x & 0xffffu) * scC; acc[1] += bf2f(vC.x >> 16) * scC;
        acc[2] += bf2f(vC.y & 0xffffu) * scC; acc[3] += bf2f(vC.y >> 16) * scC;
        acc[4] += bf2f(vC.z & 0xffffu) * scC; acc[5] += bf2f(vC.z >> 16) * scC;
        acc[6] += bf2f(vC.w & 0xffffu) * scC; acc[7] += bf2f(vC.w >> 16) * scC;
        acc[0] += bf2f(vD.x & 0xffffu) * scD; acc[1] += bf2f(vD.x >> 16) * scD;
        acc[2] += bf2f(vD.y & 0xffffu) * scD; acc[3] += bf2f(vD.y >> 16) * scD;
        acc[4] += bf2f(vD.z & 0xffffu) * scD; acc[5] += bf2f(vD.z >> 16) * scD;
        acc[6] += bf2f(vD.w & 0xffffu) * scD; acc[7] += bf2f(vD.w >> 16) * scD;

        if (cnt > BKT_C) {   // rare: scan tiny overflow list
            int no = *ovf_cnt;
            if (no > OVF_CAP) no = OVF_CAP;
            for (int i = grp; i < no; i += 4) {
                int2 p = ovf[i];
                if (p.x == widc) {
                    float sc = rsqrtf((float)(pk[p.y] & 0xffffu));
                    uint4 v = *(const uint4*)(featsh + (size_t)p.y * 256 + sub * 16);
                    acc[0] += bf2f(v.x & 0xffffu) * sc; acc[1] += bf2f(v.x >> 16) * sc;
                    acc[2] += bf2f(v.y & 0xffffu) * sc; acc[3] += bf2f(v.y >> 16) * sc;
                    acc[4] += bf2f(v.z & 0xffffu) * sc; acc[5] += bf2f(v.z >> 16) * sc;
                    acc[6] += bf2f(v.w & 0xffffu) * sc; acc[7] += bf2f(v.w >> 16) * sc;
                }
            }
        }

#pragma unroll
        for (int i = 0; i < 8; i++) {
            acc[i] += __shfl_xor(acc[i], 16);
            acc[i] += __shfl_xor(acc[i], 32);
        }
        if (grp == 0) {
            int dsrc = (int)(pkn & 0xffffu);
            float scn = (dsrc > 0) ? rsqrtf((float)dsrc) : 0.0f;
            uint4 p;
            p.x = (unsigned)f2bf(acc[0] * scn) | ((unsigned)f2bf(acc[1] * scn) << 16);
            p.y = (unsigned)f2bf(acc[2] * scn) | ((unsigned)f2bf(acc[3] * scn) << 16);
            p.z = (unsigned)f2bf(acc[4] * scn) | ((unsigned)f2bf(acc[5] * scn) << 16);
            p.w = (unsigned)f2bf(acc[6] * scn) | ((unsigned)f2bf(acc[7] * scn) << 16);
            *(uint4*)(&aggh[w * 32 + j][sub * 8]) = p;
        }
    }

    // ---------------- gemm phase: wave-private 32-row tile ----------------
    int q = grp;
    int lr = sub;
    int r0 = n0 + w * 32 + lr;      int r0c = r0 < N_NODES ? r0 : N_NODES - 1;
    int r1 = r0 + 16;               int r1c = r1 < N_NODES ? r1 : N_NODES - 1;
    const char* a0p = featsh + (size_t)r0c * 256 + q * 16;
    const char* a1p = featsh + (size_t)r1c * 256 + q * 16;

    v4f acc2[2][8];
#pragma unroll
    for (int mt = 0; mt < 2; mt++)
#pragma unroll
        for (int t = 0; t < 8; t++) acc2[mt][t] = (v4f){0.f, 0.f, 0.f, 0.f};

#pragma unroll
    for (int kk = 0; kk < 8; kk++) {
        v8s a0, a1;
        if (kk < 4) {   // aggh half from LDS
            a0 = *(const v8s*)(&aggh[w * 32 + lr][q * 8 + kk * 32]);
            a1 = *(const v8s*)(&aggh[w * 32 + 16 + lr][q * 8 + kk * 32]);
        } else {        // featsh half from ws (own rows)
            a0 = *(const v8s*)(a0p + (kk - 4) * 64);
            a1 = *(const v8s*)(a1p + (kk - 4) * 64);
        }
#pragma unroll
        for (int t = 0; t < 8; t++) {
            v8s b = *(const v8s*)(Bcat + (t * 16 + lr) * 256 + kk * 32 + q * 8);
            acc2[0][t] = __builtin_amdgcn_mfma_f32_16x16x32_bf16(a0, b, acc2[0][t], 0, 0, 0);
            acc2[1][t] = __builtin_amdgcn_mfma_f32_16x16x32_bf16(a1, b, acc2[1][t], 0, 0, 0);
        }
    }

#pragma unroll
    for (int t = 0; t < 8; t++) {
        float bv = bias[t * 16 + lr];
#pragma unroll
        for (int mt = 0; mt < 2; mt++) {
            int rowb = n0 + w * 32 + mt * 16 + q * 4;
#pragma unroll
            for (int r = 0; r < 4; r++) {
                int row = rowb + r;
                if (row < N_NODES)
                    outf[(size_t)row * 128 + t * 16 + lr] = acc2[mt][t][r] + bv;
            }
        }
    }
}

// ---------------------------------------------------------------------------
// Path A split kernels (round-3 proven bodies, d_out interleaved layout).
// ---------------------------------------------------------------------------
__device__ __forceinline__ void agg_edge(const char* outb,
                                         const unsigned int* pk,
                                         int s, int sub, float* acc) {
    float sc = rsqrtf((float)(pk[s] & 0xffffu));
    uint4 v = *(const uint4*)(outb + (size_t)s * 512 + 256 + sub * 16);
    acc[0] += bf2f(v.x & 0xffffu) * sc;
    acc[1] += bf2f(v.x >> 16) * sc;
    acc[2] += bf2f(v.y & 0xffffu) * sc;
    acc[3] += bf2f(v.y >> 16) * sc;
    acc[4] += bf2f(v.z & 0xffffu) * sc;
    acc[5] += bf2f(v.z >> 16) * sc;
    acc[6] += bf2f(v.w & 0xffffu) * sc;
    acc[7] += bf2f(v.w >> 16) * sc;
}

__device__ __forceinline__ void agg_acc(uint4 v, float sc, float* acc) {
    acc[0] += bf2f(v.x & 0xffffu) * sc;
    acc[1] += bf2f(v.x >> 16) * sc;
    acc[2] += bf2f(v.y & 0xffffu) * sc;
    acc[3] += bf2f(v.y >> 16) * sc;
    acc[4] += bf2f(v.z & 0xffffu) * sc;
    acc[5] += bf2f(v.z >> 16) * sc;
    acc[6] += bf2f(v.w & 0xffffu) * sc;
    acc[7] += bf2f(v.w >> 16) * sc;
}

__device__ __forceinline__ void agg_finish(char* outb, int wid,
                                           unsigned int pkn, int grp, int sub,
                                           float* acc) {
#pragma unroll
    for (int i = 0; i < 8; i++) {
        acc[i] += __shfl_xor(acc[i], 16);
        acc[i] += __shfl_xor(acc[i], 32);
    }
    if (grp == 0) {
        int dsrc = (int)(pkn & 0xffffu);
        float scn = (dsrc > 0) ? rsqrtf((float)dsrc) : 0.0f;
        uint4 p;
        p.x = (unsigned)f2bf(acc[0] * scn) | ((unsigned)f2bf(acc[1] * scn) << 16);
        p.y = (unsigned)f2bf(acc[2] * scn) | ((unsigned)f2bf(acc[3] * scn) << 16);
        p.z = (unsigned)f2bf(acc[4] * scn) | ((unsigned)f2bf(acc[5] * scn) << 16);
        p.w = (unsigned)f2bf(acc[6] * scn) | ((unsigned)f2bf(acc[7] * scn) << 16);
        *(uint4*)(outb + (size_t)wid * 512 + sub * 16) = p;
    }
}

__global__ __launch_bounds__(256) void k_agg_bkt(char* __restrict__ outb,
                                                 const unsigned int* __restrict__ pk,
                                                 const int* __restrict__ bucket,
                                                 const int* __restrict__ ovf_cnt,
                                                 const int2* __restrict__ ovf) {
    int wid = (int)((blockIdx.x * (unsigned)blockDim.x + threadIdx.x) >> 6);
    int lane = threadIdx.x & 63;
    if (wid >= N_NODES) return;
    int grp = lane >> 4;
    int sub = lane & 15;
    unsigned int pkn = pk[wid];
    int cnt = (int)(pkn >> 16);
    int m = cnt < BKT_C ? cnt : BKT_C;
    const int* bk = bucket + wid * BKT_C;

    int4 bq = *(const int4*)(bk + grp * 4);
    int e0 = grp * 4;

    bool a0 = e0 < m, a1 = e0 + 1 < m, a2 = e0 + 2 < m, a3 = e0 + 3 < m;
    int sA = a0 ? bq.x : 0; float gA = a0 ? 1.0f : 0.0f;
    int sB = a1 ? bq.y : 0; float gB = a1 ? 1.0f : 0.0f;
    int sC = a2 ? bq.z : 0; float gC = a2 ? 1.0f : 0.0f;
    int sD = a3 ? bq.w : 0; float gD = a3 ? 1.0f : 0.0f;

    unsigned int pA = pk[sA];
    unsigned int pB = pk[sB];
    unsigned int pC = pk[sC];
    unsigned int pD = pk[sD];
    uint4 vA = *(const uint4*)(outb + (size_t)sA * 512 + 256 + sub * 16);
    uint4 vB = *(const uint4*)(outb + (size_t)sB * 512 + 256 + sub * 16);
    uint4 vC = *(const uint4*)(outb + (size_t)sC * 512 + 256 + sub * 16);
    uint4 vD = *(const uint4*)(outb + (size_t)sD * 512 + 256 + sub * 16);

    float scA = gA * rsqrtf(fmaxf((float)(pA & 0xffffu), 1.0f));
    float scB = gB * rsqrtf(fmaxf((float)(pB & 0xffffu), 1.0f));
    float scC = gC * rsqrtf(fmaxf((float)(pC & 0xffffu), 1.0f));
    float scD = gD * rsqrtf(fmaxf((float)(pD & 0xffffu), 1.0f));

    float acc[8];
#pragma unroll
    for (int i = 0; i < 8; i++) acc[i] = 0.f;
    agg_acc(vA, scA, acc);
    agg_acc(vB, scB, acc);
    agg_acc(vC, scC, acc);
    agg_acc(vD, scD, acc);

    if (cnt > BKT_C) {
        int no = *ovf_cnt;
        if (no > OVF_CAP) no = OVF_CAP;
        for (int i = grp; i < no; i += 4) {
            int2 p = ovf[i];
            if (p.x == wid) agg_edge(outb, pk, p.y, sub, acc);
        }
    }
    agg_finish(outb, wid, pkn, grp, sub, acc);
}

// ---------------------------------------------------------------------------
// Path B fallback: exclusive scan of cnt_dst (pk hi16) -> rowptr, then fill.
// ---------------------------------------------------------------------------
__global__ __launch_bounds__(256) void k_scan1(const unsigned int* __restrict__ pk,
                                               int* __restrict__ rowptr,
                                               int* __restrict__ bsums) {
    __shared__ int sd[256];
    int t = threadIdx.x;
    int i0 = blockIdx.x * 1024 + t * 4;
    int v[4];
    int s = 0;
#pragma unroll
    for (int q = 0; q < 4; q++) {
        int i = i0 + q;
        v[q] = (i < N_NODES) ? (int)(pk[i] >> 16) : 0;
        s += v[q];
    }
    sd[t] = s;
    __syncthreads();
    for (int off = 1; off < 256; off <<= 1) {
        int y = (t >= off) ? sd[t - off] : 0;
        __syncthreads();
        sd[t] += y;
        __syncthreads();
    }
    int run = sd[t] - s;
    if (t == 255) bsums[blockIdx.x] = sd[255];
#pragma unroll
    for (int q = 0; q < 4; q++) {
        int i = i0 + q;
        if (i < N_NODES) rowptr[i] = run;
        run += v[q];
    }
}

__global__ __launch_bounds__(128) void k_scan2(int* __restrict__ bsums) {
    __shared__ int sd[128];
    int t = threadIdx.x;
    int v = (t < NB) ? bsums[t] : 0;
    sd[t] = v;
    __syncthreads();
    for (int off = 1; off < 128; off <<= 1) {
        int y = (t >= off) ? sd[t - off] : 0;
        __syncthreads();
        sd[t] += y;
        __syncthreads();
    }
    if (t < NB) bsums[t] = sd[t] - v;
}

__global__ __launch_bounds__(256) void k_scan3(const int* __restrict__ bsums,
                                               int* __restrict__ rowptr) {
    int add = bsums[blockIdx.x];
    int i0 = blockIdx.x * 1024 + threadIdx.x * 4;
#pragma unroll
    for (int q = 0; q < 4; q++) {
        int i = i0 + q;
        if (i < N_NODES) rowptr[i] += add;
    }
}

__global__ __launch_bounds__(256) void k_fill(const int* __restrict__ src,
                                              const int* __restrict__ dst,
                                              int* __restrict__ rowptr,
                                              int* __restrict__ csr_src) {
    int e = blockIdx.x * blockDim.x + threadIdx.x;
    if (e < N_EDGES) {
        int p = atomicAdd(&rowptr[dst[e]], 1);
        csr_src[p] = src[e];
    }
}

// Path B: end-pointer CSR aggregation
__global__ __launch_bounds__(256) void k_agg_csr(char* __restrict__ outb,
                                                 const unsigned int* __restrict__ pk,
                                                 const int* __restrict__ rowptr,
                                                 const int* __restrict__ csr_src) {
    int wid = (int)((blockIdx.x * (unsigned)blockDim.x + threadIdx.x) >> 6);
    int lane = threadIdx.x & 63;
    if (wid >= N_NODES) return;
    int grp = lane >> 4;
    int sub = lane & 15;
    int start = (wid == 0) ? 0 : rowptr[wid - 1];
    int end = rowptr[wid];
    float acc[8];
#pragma unroll
    for (int i = 0; i < 8; i++) acc[i] = 0.f;
    for (int base = start; base < end; base += 4) {
        int e = base + grp;
        if (e < end) agg_edge(outb, pk, csr_src[e], sub, acc);
    }
    agg_finish(outb, wid, pk[wid], grp, sub, acc);
}

// ---------------------------------------------------------------------------
// k_gemm (Path A/B): out[n,:] = Arow[n] @ Bcat^T + bias, MFMA 16x16x32 bf16,
// K=256. Arow = packed [aggh|featsh] bf16 rows in d_out; overwritten in
// place with the fp32 result.
// ---------------------------------------------------------------------------
__global__ __launch_bounds__(256) void k_gemm(const unsigned short* __restrict__ Bcat,
                                              const float* __restrict__ bias,
                                              float* __restrict__ outf) {
    __shared__ unsigned short Bl[128][264];
    const char* Ab = (const char*)outf;
    int tid = threadIdx.x;
    int lane = tid & 63;
    int w = tid >> 6;
    int n0 = blockIdx.x * 128;

    for (int i = tid; i < 128 * 32; i += 256) {
        int r = i >> 5, c = i & 31;
        *(uint4*)(&Bl[r][c * 8]) = *(const uint4*)(Bcat + r * 256 + c * 8);
    }
    __syncthreads();

    int q = lane >> 4;
    int lr = lane & 15;

    int r0 = n0 + w * 32 + lr;      if (r0 > N_NODES - 1) r0 = N_NODES - 1;
    int r1 = n0 + w * 32 + 16 + lr; if (r1 > N_NODES - 1) r1 = N_NODES - 1;
    const char* a0p = Ab + (size_t)r0 * 512 + q * 16;
    const char* a1p = Ab + (size_t)r1 * 512 + q * 16;

    v4f acc[2][8];
#pragma unroll
    for (int mt = 0; mt < 2; mt++)
#pragma unroll
        for (int t = 0; t < 8; t++) acc[mt][t] = (v4f){0.f, 0.f, 0.f, 0.f};

#pragma unroll
    for (int kk = 0; kk < 8; kk++) {
        v8s a0 = *(const v8s*)(a0p + kk * 64);
        v8s a1 = *(const v8s*)(a1p + kk * 64);
#pragma unroll
        for (int t = 0; t < 8; t++) {
            v8s b = *(const v8s*)(&Bl[t * 16 + lr][kk * 32 + q * 8]);
            acc[0][t] = __builtin_amdgcn_mfma_f32_16x16x32_bf16(a0, b, acc[0][t], 0, 0, 0);
            acc[1][t] = __builtin_amdgcn_mfma_f32_16x16x32_bf16(a1, b, acc[1][t], 0, 0, 0);
        }
    }

#pragma unroll
    for (int t = 0; t < 8; t++) {
        float bv = bias[t * 16 + lr];
#pragma unroll
        for (int mt = 0; mt < 2; mt++) {
            int rowb = n0 + w * 32 + mt * 16 + q * 4;
#pragma unroll
            for (int r = 0; r < 4; r++) {
                int row = rowb + r;
                if (row < N_NODES)
                    outf[(size_t)row * 128 + t * 16 + lr] = acc[mt][t][r] + bv;
            }
        }
    }
}

// ---------------------------------------------------------------------------
extern "C" void kernel_launch(void* const* d_in, const int* in_sizes, int n_in,
                              void* d_out, int out_size, void* d_ws, size_t ws_size,
                              hipStream_t stream) {
    const float* feats = (const float*)d_in[0];
    const int*   src   = (const int*)d_in[1];
    const int*   dst   = (const int*)d_in[2];
    const float* Wskip = (const float*)d_in[3];
    const float* bskip = (const float*)d_in[4];
    const float* Wmsg  = (const float*)d_in[5];
    const float* bmsg  = (const float*)d_in[6];

    char* w = (char*)d_ws;

    // Path C layout (fused, featsh out-of-place), needs 32,728,320 B:
    //   [0,      400000)   uint pk[N]
    //   [400000, 400128)   int  ovf_cnt (+pad)
    //   [400128, 465664)   ushort Bcat[128*256]
    //   [465664, 466176)   float bias[128]
    //   [466176, 6866176)  int  bucket[N*16]
    //   [6866176,7128320)  int2 ovf[32768]
    //   [7128320,32728320) ushort featsh[N*128]  (256B rows, compact)
    // Path A layout (split, featsh interleaved in d_out), needs 7,128,320 B.
    // Path B layout (count+scan+fill), needs 3,426,688 B.
    bool pathC = ws_size >= (size_t)32728320;
    bool pathA = ws_size >= (size_t)7128320;

    if (pathC) {
        unsigned int*   pk      = (unsigned int*)w;
        int*            ovf_cnt = (int*)(w + 400000);
        unsigned short* Bcat    = (unsigned short*)(w + 400128);
        float*          bias    = (float*)(w + 465664);
        int*            bucket  = (int*)(w + 466176);
        int2*           ovf     = (int2*)(w + 6866176);
        char*           featsh  = w + 7128320;

        hipLaunchKernelGGL(k_zero, dim3((N_NODES / 4 + 255) / 256), dim3(256), 0,
                           stream, (int4*)pk, ovf_cnt);
        hipLaunchKernelGGL(k_pre, dim3((N_NODES * (D / 8) + 255) / 256), dim3(256),
                           0, stream, feats, Wmsg, Wskip, bmsg, bskip, src, dst, pk,
                           Bcat, bias, featsh, 256, bucket, ovf_cnt, ovf);
        hipLaunchKernelGGL(k_fused2, dim3((N_NODES + 127) / 128), dim3(256), 0,
                           stream, featsh, pk, bucket, ovf_cnt, ovf, Bcat, bias,
                           (float*)d_out);
    } else if (pathA) {
        unsigned int*   pk      = (unsigned int*)w;
        int*            ovf_cnt = (int*)(w + 400000);
        unsigned short* Bcat    = (unsigned short*)(w + 400128);
        float*          bias    = (float*)(w + 465664);
        int*            bucket  = (int*)(w + 466176);
        int2*           ovf     = (int2*)(w + 6866176);

        hipLaunchKernelGGL(k_zero, dim3((N_NODES / 4 + 255) / 256), dim3(256), 0,
                           stream, (int4*)pk, ovf_cnt);
        hipLaunchKernelGGL(k_pre, dim3((N_NODES * (D / 8) + 255) / 256), dim3(256),
                           0, stream, feats, Wmsg, Wskip, bmsg, bskip, src, dst, pk,
                           Bcat, bias, (char*)d_out + 256, 512, bucket, ovf_cnt, ovf);
        hipLaunchKernelGGL(k_agg_bkt, dim3((N_NODES * 64 + 255) / 256), dim3(256), 0,
                           stream, (char*)d_out, pk, bucket, ovf_cnt, ovf);
        hipLaunchKernelGGL(k_gemm, dim3((N_NODES + 127) / 128), dim3(256), 0, stream,
                           Bcat, bias, (float*)d_out);
    } else {
        unsigned int*   pk      = (unsigned int*)w;
        int*            rowptr  = (int*)(w + 400000);
        int*            bsums   = (int*)(w + 800128);
        unsigned short* Bcat    = (unsigned short*)(w + 800640);
        float*          bias    = (float*)(w + 866176);
        int*            csr_src = (int*)(w + 866688);

        hipLaunchKernelGGL(k_zero, dim3((N_NODES / 4 + 255) / 256), dim3(256), 0,
                           stream, (int4*)pk, (int*)(w + 400000) /*unused slot*/);
        hipLaunchKernelGGL(k_pre, dim3((N_NODES * (D / 8) + 255) / 256), dim3(256),
                           0, stream, feats, Wmsg, Wskip, bmsg, bskip, src, dst, pk,
                           Bcat, bias, (char*)d_out + 256, 512, (int*)nullptr,
                           (int*)nullptr, (int2*)nullptr);
        hipLaunchKernelGGL(k_scan1, dim3(NB), dim3(256), 0, stream, pk, rowptr,
                           bsums);
        hipLaunchKernelGGL(k_scan2, dim3(1), dim3(128), 0, stream, bsums);
        hipLaunchKernelGGL(k_scan3, dim3(NB), dim3(256), 0, stream, bsums, rowptr);
        hipLaunchKernelGGL(k_fill, dim3((N_EDGES + 255) / 256), dim3(256), 0, stream,
                           src, dst, rowptr, csr_src);
        hipLaunchKernelGGL(k_agg_csr, dim3((N_NODES * 64 + 255) / 256), dim3(256), 0,
                           stream, (char*)d_out, pk, rowptr, csr_src);
        hipLaunchKernelGGL(k_gemm, dim3((N_NODES + 127) / 128), dim3(256), 0, stream,
                           Bcat, bias, (float*)d_out);
    }
}

// Round 7
// 232.569 us; speedup vs baseline: 1.2171x; 1.1608x over previous
//
#include <hip/hip_runtime.h>

#define N_NODES 100000
#define N_EDGES 640000
#define D 128
#define NB ((N_NODES + 1023) / 1024)   // 98 scan blocks
#define BKT_C 16                        // bucket capacity: 16 ints = one 64B line
#define OVF_CAP 32768

typedef short v8s __attribute__((ext_vector_type(8)));
typedef float v4f __attribute__((ext_vector_type(4)));

__device__ __forceinline__ unsigned short f2bf(float x) {
    unsigned int u = __builtin_bit_cast(unsigned int, x);
    u += 0x7fffu + ((u >> 16) & 1u);   // RNE
    return (unsigned short)(u >> 16);
}
__device__ __forceinline__ float bf2f(unsigned int hi) {
    return __builtin_bit_cast(float, hi << 16);
}

// ---------------------------------------------------------------------------
// k_zero: zero pk[N] + (Path C) bucket[N*16] + ovf_cnt.
// KEEP AS A KERNEL (not hipMemsetAsync): stores write-allocate near the
// coherence point so k_pre's atomics hit warm lines (rounds 1-2 lesson).
// Bucket zeroing (Path C) lets k_agg_c issue gathers UNCONDITIONALLY off the
// bucket line (stale slots -> node 0, gated by scale=0) — removes one
// serialization level from the gather chain.
// ---------------------------------------------------------------------------
__global__ __launch_bounds__(256) void k_zero(int4* __restrict__ pk4,
                                              int4* __restrict__ bkt4,
                                              int* __restrict__ ovf_cnt) {
    int i = blockIdx.x * blockDim.x + threadIdx.x;
    if (i < N_NODES / 4) pk4[i] = make_int4(0, 0, 0, 0);
    if (bkt4 && i < N_NODES * BKT_C / 4) bkt4[i] = make_int4(0, 0, 0, 0);
    if (i == 0 && ovf_cnt) *ovf_cnt = 0;
}

// ---------------------------------------------------------------------------
// k_pre: featsh bf16 pack to fsbase + row*fs_stride (Path C: compact ws
// array stride 256; Path A/B: d_out+256 stride 512); weights -> Bcat bf16;
// bias=bm+bs; first 640K threads count degrees and scatter src into per-dst
// 16-entry INT buckets. Round-4 lesson: scattered-atomic fabric cost scales
// with op count, not element size — no extra streams.
// ---------------------------------------------------------------------------
__global__ __launch_bounds__(256) void k_pre(const float* __restrict__ feats,
                                             const float* __restrict__ Wm,
                                             const float* __restrict__ Ws,
                                             const float* __restrict__ bmsg,
                                             const float* __restrict__ bskip,
                                             const int* __restrict__ src,
                                             const int* __restrict__ dst,
                                             unsigned int* __restrict__ pk,
                                             unsigned short* __restrict__ Bcat,
                                             float* __restrict__ bias,
                                             char* __restrict__ fsbase,
                                             int fs_stride,
                                             int* __restrict__ bucket,
                                             int* __restrict__ ovf_cnt,
                                             int2* __restrict__ ovf) {
    int i = blockIdx.x * blockDim.x + threadIdx.x;
    if (i < D * D) {
        int j = i >> 7;
        int k = i & 127;
        Bcat[j * 256 + k]       = f2bf(Wm[i]);
        Bcat[j * 256 + 128 + k] = f2bf(Ws[i]);
    }
    if (i < D) bias[i] = bmsg[i] + bskip[i];
    if (i < N_EDGES) {
        int s = src[i];
        int d = dst[i];
        atomicAdd(&pk[s], 1u);
        unsigned int old = atomicAdd(&pk[d], 0x10000u);
        if (bucket) {
            unsigned int p = old >> 16;
            if (p < BKT_C) {
                bucket[d * BKT_C + (int)p] = s;
            } else {
                int q = atomicAdd(ovf_cnt, 1);
                if (q < OVF_CAP) ovf[q] = make_int2(d, s);
            }
        }
    }
    int g = i * 8;
    int row = g >> 7;
    int col = g & 127;
    if (row < N_NODES) {
        const float4* sp = (const float4*)(feats + g);
        float4 x = sp[0], y = sp[1];
        uint4 p;
        p.x = (unsigned)f2bf(x.x) | ((unsigned)f2bf(x.y) << 16);
        p.y = (unsigned)f2bf(x.z) | ((unsigned)f2bf(x.w) << 16);
        p.z = (unsigned)f2bf(y.x) | ((unsigned)f2bf(y.y) << 16);
        p.w = (unsigned)f2bf(y.z) | ((unsigned)f2bf(y.w) << 16);
        *(uint4*)(fsbase + (size_t)row * fs_stride + col * 2) = p;
    }
}

// ---------------------------------------------------------------------------
// k_agg_c (Path C): 1 wave per node — 100k waves / 25000 blocks, the
// proven-occupancy shape (round-6 lesson: the 782-block fused kernel was
// request-starved at 21% occupancy). Gathers from COMPACT bf16 featsh
// (round-6 verified FETCH win). Bucket is zero-initialized, so all 8 loads
// (4 pk + 4 rows) issue unconditionally right after the bucket line lands;
// gating is applied to the scale only, off the critical issue path.
// aggh -> FIRST 256B of each 512B d_out row (race-free: k_gemm_c block n
// reads only its own rows' aggh before overwriting them).
// ---------------------------------------------------------------------------
__global__ __launch_bounds__(256) void k_agg_c(char* __restrict__ outb,
                                               const char* __restrict__ featsh,
                                               const unsigned int* __restrict__ pk,
                                               const int* __restrict__ bucket,
                                               const int* __restrict__ ovf_cnt,
                                               const int2* __restrict__ ovf) {
    int wid = (int)((blockIdx.x * (unsigned)blockDim.x + threadIdx.x) >> 6);
    int lane = threadIdx.x & 63;
    if (wid >= N_NODES) return;
    int grp = lane >> 4;
    int sub = lane & 15;

    // two independent loads issue immediately
    int4 bq = *(const int4*)(bucket + wid * BKT_C + grp * 4);
    unsigned int pkn = pk[wid];

    // unconditional: stale slots are 0 (zero-init), node 0's row is valid
    int sA = bq.x, sB = bq.y, sC = bq.z, sD = bq.w;
    unsigned int pA = pk[sA];
    unsigned int pB = pk[sB];
    unsigned int pC = pk[sC];
    unsigned int pD = pk[sD];
    uint4 vA = *(const uint4*)(featsh + (size_t)sA * 256 + sub * 16);
    uint4 vB = *(const uint4*)(featsh + (size_t)sB * 256 + sub * 16);
    uint4 vC = *(const uint4*)(featsh + (size_t)sC * 256 + sub * 16);
    uint4 vD = *(const uint4*)(featsh + (size_t)sD * 256 + sub * 16);

    // gate math runs while loads are in flight
    int cnt = (int)(pkn >> 16);
    int m = cnt < BKT_C ? cnt : BKT_C;
    int e0 = grp * 4;
    float gA = (e0 < m) ? 1.0f : 0.0f;
    float gB = (e0 + 1 < m) ? 1.0f : 0.0f;
    float gC = (e0 + 2 < m) ? 1.0f : 0.0f;
    float gD = (e0 + 3 < m) ? 1.0f : 0.0f;

    float scA = gA * rsqrtf(fmaxf((float)(pA & 0xffffu), 1.0f));
    float scB = gB * rsqrtf(fmaxf((float)(pB & 0xffffu), 1.0f));
    float scC = gC * rsqrtf(fmaxf((float)(pC & 0xffffu), 1.0f));
    float scD = gD * rsqrtf(fmaxf((float)(pD & 0xffffu), 1.0f));

    float acc[8];
#pragma unroll
    for (int i = 0; i < 8; i++) acc[i] = 0.f;
    acc[0] += bf2f(vA.x & 0xffffu) * scA; acc[1] += bf2f(vA.x >> 16) * scA;
    acc[2] += bf2f(vA.y & 0xffffu) * scA; acc[3] += bf2f(vA.y >> 16) * scA;
    acc[4] += bf2f(vA.z & 0xffffu) * scA; acc[5] += bf2f(vA.z >> 16) * scA;
    acc[6] += bf2f(vA.w & 0xffffu) * scA; acc[7] += bf2f(vA.w >> 16) * scA;
    acc[0] += bf2f(vB.x & 0xffffu) * scB; acc[1] += bf2f(vB.x >> 16) * scB;
    acc[2] += bf2f(vB.y & 0xffffu) * scB; acc[3] += bf2f(vB.y >> 16) * scB;
    acc[4] += bf2f(vB.z & 0xffffu) * scB; acc[5] += bf2f(vB.z >> 16) * scB;
    acc[6] += bf2f(vB.w & 0xffffu) * scB; acc[7] += bf2f(vB.w >> 16) * scB;
    acc[0] += bf2f(vC.x & 0xffffu) * scC; acc[1] += bf2f(vC.x >> 16) * scC;
    acc[2] += bf2f(vC.y & 0xffffu) * scC; acc[3] += bf2f(vC.y >> 16) * scC;
    acc[4] += bf2f(vC.z & 0xffffu) * scC; acc[5] += bf2f(vC.z >> 16) * scC;
    acc[6] += bf2f(vC.w & 0xffffu) * scC; acc[7] += bf2f(vC.w >> 16) * scC;
    acc[0] += bf2f(vD.x & 0xffffu) * scD; acc[1] += bf2f(vD.x >> 16) * scD;
    acc[2] += bf2f(vD.y & 0xffffu) * scD; acc[3] += bf2f(vD.y >> 16) * scD;
    acc[4] += bf2f(vD.z & 0xffffu) * scD; acc[5] += bf2f(vD.z >> 16) * scD;
    acc[6] += bf2f(vD.w & 0xffffu) * scD; acc[7] += bf2f(vD.w >> 16) * scD;

    if (cnt > BKT_C) {   // rare: scan tiny overflow list
        int no = *ovf_cnt;
        if (no > OVF_CAP) no = OVF_CAP;
        for (int i = grp; i < no; i += 4) {
            int2 p = ovf[i];
            if (p.x == wid) {
                float sc = rsqrtf((float)(pk[p.y] & 0xffffu));
                uint4 v = *(const uint4*)(featsh + (size_t)p.y * 256 + sub * 16);
                acc[0] += bf2f(v.x & 0xffffu) * sc; acc[1] += bf2f(v.x >> 16) * sc;
                acc[2] += bf2f(v.y & 0xffffu) * sc; acc[3] += bf2f(v.y >> 16) * sc;
                acc[4] += bf2f(v.z & 0xffffu) * sc; acc[5] += bf2f(v.z >> 16) * sc;
                acc[6] += bf2f(v.w & 0xffffu) * sc; acc[7] += bf2f(v.w >> 16) * sc;
            }
        }
    }

#pragma unroll
    for (int i = 0; i < 8; i++) {
        acc[i] += __shfl_xor(acc[i], 16);
        acc[i] += __shfl_xor(acc[i], 32);
    }
    if (grp == 0) {
        int dsrc = (int)(pkn & 0xffffu);
        float scn = (dsrc > 0) ? rsqrtf((float)dsrc) : 0.0f;
        uint4 p;
        p.x = (unsigned)f2bf(acc[0] * scn) | ((unsigned)f2bf(acc[1] * scn) << 16);
        p.y = (unsigned)f2bf(acc[2] * scn) | ((unsigned)f2bf(acc[3] * scn) << 16);
        p.z = (unsigned)f2bf(acc[4] * scn) | ((unsigned)f2bf(acc[5] * scn) << 16);
        p.w = (unsigned)f2bf(acc[6] * scn) | ((unsigned)f2bf(acc[7] * scn) << 16);
        *(uint4*)(outb + (size_t)wid * 512 + sub * 16) = p;   // aggh, bytes 0-255
    }
}

// ---------------------------------------------------------------------------
// k_gemm_c (Path C): out[n,:] = [aggh(d_out) | featsh(ws)] @ Bcat^T + bias.
// MFMA 16x16x32 bf16, K=256. Safe to overwrite d_out: each wave's A-loads
// are consumed by MFMAs before its C-store data exists, and A-rows are
// wave-local (tail clamping reads may race but feed only discarded lanes).
// ---------------------------------------------------------------------------
__global__ __launch_bounds__(256) void k_gemm_c(const char* __restrict__ featsh,
                                                const unsigned short* __restrict__ Bcat,
                                                const float* __restrict__ bias,
                                                float* __restrict__ outf) {
    __shared__ unsigned short Bl[128][264];
    const char* Ab = (const char*)outf;
    int tid = threadIdx.x;
    int lane = tid & 63;
    int w = tid >> 6;
    int n0 = blockIdx.x * 128;

    for (int i = tid; i < 128 * 32; i += 256) {
        int r = i >> 5, c = i & 31;
        *(uint4*)(&Bl[r][c * 8]) = *(const uint4*)(Bcat + r * 256 + c * 8);
    }
    __syncthreads();

    int q = lane >> 4;
    int lr = lane & 15;

    int r0 = n0 + w * 32 + lr;      if (r0 > N_NODES - 1) r0 = N_NODES - 1;
    int r1 = n0 + w * 32 + 16 + lr; if (r1 > N_NODES - 1) r1 = N_NODES - 1;
    const char* g0p = Ab + (size_t)r0 * 512 + q * 16;        // aggh half
    const char* g1p = Ab + (size_t)r1 * 512 + q * 16;
    const char* f0p = featsh + (size_t)r0 * 256 + q * 16;    // featsh half
    const char* f1p = featsh + (size_t)r1 * 256 + q * 16;

    v4f acc[2][8];
#pragma unroll
    for (int mt = 0; mt < 2; mt++)
#pragma unroll
        for (int t = 0; t < 8; t++) acc[mt][t] = (v4f){0.f, 0.f, 0.f, 0.f};

#pragma unroll
    for (int kk = 0; kk < 8; kk++) {
        v8s a0, a1;
        if (kk < 4) {
            a0 = *(const v8s*)(g0p + kk * 64);
            a1 = *(const v8s*)(g1p + kk * 64);
        } else {
            a0 = *(const v8s*)(f0p + (kk - 4) * 64);
            a1 = *(const v8s*)(f1p + (kk - 4) * 64);
        }
#pragma unroll
        for (int t = 0; t < 8; t++) {
            v8s b = *(const v8s*)(&Bl[t * 16 + lr][kk * 32 + q * 8]);
            acc[0][t] = __builtin_amdgcn_mfma_f32_16x16x32_bf16(a0, b, acc[0][t], 0, 0, 0);
            acc[1][t] = __builtin_amdgcn_mfma_f32_16x16x32_bf16(a1, b, acc[1][t], 0, 0, 0);
        }
    }

#pragma unroll
    for (int t = 0; t < 8; t++) {
        float bv = bias[t * 16 + lr];
#pragma unroll
        for (int mt = 0; mt < 2; mt++) {
            int rowb = n0 + w * 32 + mt * 16 + q * 4;
#pragma unroll
            for (int r = 0; r < 4; r++) {
                int row = rowb + r;
                if (row < N_NODES)
                    outf[(size_t)row * 128 + t * 16 + lr] = acc[mt][t][r] + bv;
            }
        }
    }
}

// ---------------------------------------------------------------------------
// Path A split kernels (round-3 proven bodies, d_out interleaved layout).
// ---------------------------------------------------------------------------
__device__ __forceinline__ void agg_edge(const char* outb,
                                         const unsigned int* pk,
                                         int s, int sub, float* acc) {
    float sc = rsqrtf((float)(pk[s] & 0xffffu));
    uint4 v = *(const uint4*)(outb + (size_t)s * 512 + 256 + sub * 16);
    acc[0] += bf2f(v.x & 0xffffu) * sc;
    acc[1] += bf2f(v.x >> 16) * sc;
    acc[2] += bf2f(v.y & 0xffffu) * sc;
    acc[3] += bf2f(v.y >> 16) * sc;
    acc[4] += bf2f(v.z & 0xffffu) * sc;
    acc[5] += bf2f(v.z >> 16) * sc;
    acc[6] += bf2f(v.w & 0xffffu) * sc;
    acc[7] += bf2f(v.w >> 16) * sc;
}

__device__ __forceinline__ void agg_acc(uint4 v, float sc, float* acc) {
    acc[0] += bf2f(v.x & 0xffffu) * sc;
    acc[1] += bf2f(v.x >> 16) * sc;
    acc[2] += bf2f(v.y & 0xffffu) * sc;
    acc[3] += bf2f(v.y >> 16) * sc;
    acc[4] += bf2f(v.z & 0xffffu) * sc;
    acc[5] += bf2f(v.z >> 16) * sc;
    acc[6] += bf2f(v.w & 0xffffu) * sc;
    acc[7] += bf2f(v.w >> 16) * sc;
}

__device__ __forceinline__ void agg_finish(char* outb, int wid,
                                           unsigned int pkn, int grp, int sub,
                                           float* acc) {
#pragma unroll
    for (int i = 0; i < 8; i++) {
        acc[i] += __shfl_xor(acc[i], 16);
        acc[i] += __shfl_xor(acc[i], 32);
    }
    if (grp == 0) {
        int dsrc = (int)(pkn & 0xffffu);
        float scn = (dsrc > 0) ? rsqrtf((float)dsrc) : 0.0f;
        uint4 p;
        p.x = (unsigned)f2bf(acc[0] * scn) | ((unsigned)f2bf(acc[1] * scn) << 16);
        p.y = (unsigned)f2bf(acc[2] * scn) | ((unsigned)f2bf(acc[3] * scn) << 16);
        p.z = (unsigned)f2bf(acc[4] * scn) | ((unsigned)f2bf(acc[5] * scn) << 16);
        p.w = (unsigned)f2bf(acc[6] * scn) | ((unsigned)f2bf(acc[7] * scn) << 16);
        *(uint4*)(outb + (size_t)wid * 512 + sub * 16) = p;
    }
}

__global__ __launch_bounds__(256) void k_agg_bkt(char* __restrict__ outb,
                                                 const unsigned int* __restrict__ pk,
                                                 const int* __restrict__ bucket,
                                                 const int* __restrict__ ovf_cnt,
                                                 const int2* __restrict__ ovf) {
    int wid = (int)((blockIdx.x * (unsigned)blockDim.x + threadIdx.x) >> 6);
    int lane = threadIdx.x & 63;
    if (wid >= N_NODES) return;
    int grp = lane >> 4;
    int sub = lane & 15;
    unsigned int pkn = pk[wid];
    int cnt = (int)(pkn >> 16);
    int m = cnt < BKT_C ? cnt : BKT_C;
    const int* bk = bucket + wid * BKT_C;

    int4 bq = *(const int4*)(bk + grp * 4);
    int e0 = grp * 4;

    bool a0 = e0 < m, a1 = e0 + 1 < m, a2 = e0 + 2 < m, a3 = e0 + 3 < m;
    int sA = a0 ? bq.x : 0; float gA = a0 ? 1.0f : 0.0f;
    int sB = a1 ? bq.y : 0; float gB = a1 ? 1.0f : 0.0f;
    int sC = a2 ? bq.z : 0; float gC = a2 ? 1.0f : 0.0f;
    int sD = a3 ? bq.w : 0; float gD = a3 ? 1.0f : 0.0f;

    unsigned int pA = pk[sA];
    unsigned int pB = pk[sB];
    unsigned int pC = pk[sC];
    unsigned int pD = pk[sD];
    uint4 vA = *(const uint4*)(outb + (size_t)sA * 512 + 256 + sub * 16);
    uint4 vB = *(const uint4*)(outb + (size_t)sB * 512 + 256 + sub * 16);
    uint4 vC = *(const uint4*)(outb + (size_t)sC * 512 + 256 + sub * 16);
    uint4 vD = *(const uint4*)(outb + (size_t)sD * 512 + 256 + sub * 16);

    float scA = gA * rsqrtf(fmaxf((float)(pA & 0xffffu), 1.0f));
    float scB = gB * rsqrtf(fmaxf((float)(pB & 0xffffu), 1.0f));
    float scC = gC * rsqrtf(fmaxf((float)(pC & 0xffffu), 1.0f));
    float scD = gD * rsqrtf(fmaxf((float)(pD & 0xffffu), 1.0f));

    float acc[8];
#pragma unroll
    for (int i = 0; i < 8; i++) acc[i] = 0.f;
    agg_acc(vA, scA, acc);
    agg_acc(vB, scB, acc);
    agg_acc(vC, scC, acc);
    agg_acc(vD, scD, acc);

    if (cnt > BKT_C) {
        int no = *ovf_cnt;
        if (no > OVF_CAP) no = OVF_CAP;
        for (int i = grp; i < no; i += 4) {
            int2 p = ovf[i];
            if (p.x == wid) agg_edge(outb, pk, p.y, sub, acc);
        }
    }
    agg_finish(outb, wid, pkn, grp, sub, acc);
}

// ---------------------------------------------------------------------------
// Path B fallback: exclusive scan of cnt_dst (pk hi16) -> rowptr, then fill.
// ---------------------------------------------------------------------------
__global__ __launch_bounds__(256) void k_scan1(const unsigned int* __restrict__ pk,
                                               int* __restrict__ rowptr,
                                               int* __restrict__ bsums) {
    __shared__ int sd[256];
    int t = threadIdx.x;
    int i0 = blockIdx.x * 1024 + t * 4;
    int v[4];
    int s = 0;
#pragma unroll
    for (int q = 0; q < 4; q++) {
        int i = i0 + q;
        v[q] = (i < N_NODES) ? (int)(pk[i] >> 16) : 0;
        s += v[q];
    }
    sd[t] = s;
    __syncthreads();
    for (int off = 1; off < 256; off <<= 1) {
        int y = (t >= off) ? sd[t - off] : 0;
        __syncthreads();
        sd[t] += y;
        __syncthreads();
    }
    int run = sd[t] - s;
    if (t == 255) bsums[blockIdx.x] = sd[255];
#pragma unroll
    for (int q = 0; q < 4; q++) {
        int i = i0 + q;
        if (i < N_NODES) rowptr[i] = run;
        run += v[q];
    }
}

__global__ __launch_bounds__(128) void k_scan2(int* __restrict__ bsums) {
    __shared__ int sd[128];
    int t = threadIdx.x;
    int v = (t < NB) ? bsums[t] : 0;
    sd[t] = v;
    __syncthreads();
    for (int off = 1; off < 128; off <<= 1) {
        int y = (t >= off) ? sd[t - off] : 0;
        __syncthreads();
        sd[t] += y;
        __syncthreads();
    }
    if (t < NB) bsums[t] = sd[t] - v;
}

__global__ __launch_bounds__(256) void k_scan3(const int* __restrict__ bsums,
                                               int* __restrict__ rowptr) {
    int add = bsums[blockIdx.x];
    int i0 = blockIdx.x * 1024 + threadIdx.x * 4;
#pragma unroll
    for (int q = 0; q < 4; q++) {
        int i = i0 + q;
        if (i < N_NODES) rowptr[i] += add;
    }
}

__global__ __launch_bounds__(256) void k_fill(const int* __restrict__ src,
                                              const int* __restrict__ dst,
                                              int* __restrict__ rowptr,
                                              int* __restrict__ csr_src) {
    int e = blockIdx.x * blockDim.x + threadIdx.x;
    if (e < N_EDGES) {
        int p = atomicAdd(&rowptr[dst[e]], 1);
        csr_src[p] = src[e];
    }
}

// Path B: end-pointer CSR aggregation
__global__ __launch_bounds__(256) void k_agg_csr(char* __restrict__ outb,
                                                 const unsigned int* __restrict__ pk,
                                                 const int* __restrict__ rowptr,
                                                 const int* __restrict__ csr_src) {
    int wid = (int)((blockIdx.x * (unsigned)blockDim.x + threadIdx.x) >> 6);
    int lane = threadIdx.x & 63;
    if (wid >= N_NODES) return;
    int grp = lane >> 4;
    int sub = lane & 15;
    int start = (wid == 0) ? 0 : rowptr[wid - 1];
    int end = rowptr[wid];
    float acc[8];
#pragma unroll
    for (int i = 0; i < 8; i++) acc[i] = 0.f;
    for (int base = start; base < end; base += 4) {
        int e = base + grp;
        if (e < end) agg_edge(outb, pk, csr_src[e], sub, acc);
    }
    agg_finish(outb, wid, pk[wid], grp, sub, acc);
}

// ---------------------------------------------------------------------------
// k_gemm (Path A/B): out[n,:] = Arow[n] @ Bcat^T + bias, MFMA 16x16x32 bf16,
// K=256. Arow = packed [aggh|featsh] bf16 rows in d_out; overwritten in
// place with the fp32 result.
// ---------------------------------------------------------------------------
__global__ __launch_bounds__(256) void k_gemm(const unsigned short* __restrict__ Bcat,
                                              const float* __restrict__ bias,
                                              float* __restrict__ outf) {
    __shared__ unsigned short Bl[128][264];
    const char* Ab = (const char*)outf;
    int tid = threadIdx.x;
    int lane = tid & 63;
    int w = tid >> 6;
    int n0 = blockIdx.x * 128;

    for (int i = tid; i < 128 * 32; i += 256) {
        int r = i >> 5, c = i & 31;
        *(uint4*)(&Bl[r][c * 8]) = *(const uint4*)(Bcat + r * 256 + c * 8);
    }
    __syncthreads();

    int q = lane >> 4;
    int lr = lane & 15;

    int r0 = n0 + w * 32 + lr;      if (r0 > N_NODES - 1) r0 = N_NODES - 1;
    int r1 = n0 + w * 32 + 16 + lr; if (r1 > N_NODES - 1) r1 = N_NODES - 1;
    const char* a0p = Ab + (size_t)r0 * 512 + q * 16;
    const char* a1p = Ab + (size_t)r1 * 512 + q * 16;

    v4f acc[2][8];
#pragma unroll
    for (int mt = 0; mt < 2; mt++)
#pragma unroll
        for (int t = 0; t < 8; t++) acc[mt][t] = (v4f){0.f, 0.f, 0.f, 0.f};

#pragma unroll
    for (int kk = 0; kk < 8; kk++) {
        v8s a0 = *(const v8s*)(a0p + kk * 64);
        v8s a1 = *(const v8s*)(a1p + kk * 64);
#pragma unroll
        for (int t = 0; t < 8; t++) {
            v8s b = *(const v8s*)(&Bl[t * 16 + lr][kk * 32 + q * 8]);
            acc[0][t] = __builtin_amdgcn_mfma_f32_16x16x32_bf16(a0, b, acc[0][t], 0, 0, 0);
            acc[1][t] = __builtin_amdgcn_mfma_f32_16x16x32_bf16(a1, b, acc[1][t], 0, 0, 0);
        }
    }

#pragma unroll
    for (int t = 0; t < 8; t++) {
        float bv = bias[t * 16 + lr];
#pragma unroll
        for (int mt = 0; mt < 2; mt++) {
            int rowb = n0 + w * 32 + mt * 16 + q * 4;
#pragma unroll
            for (int r = 0; r < 4; r++) {
                int row = rowb + r;
                if (row < N_NODES)
                    outf[(size_t)row * 128 + t * 16 + lr] = acc[mt][t][r] + bv;
            }
        }
    }
}

// ---------------------------------------------------------------------------
extern "C" void kernel_launch(void* const* d_in, const int* in_sizes, int n_in,
                              void* d_out, int out_size, void* d_ws, size_t ws_size,
                              hipStream_t stream) {
    const float* feats = (const float*)d_in[0];
    const int*   src   = (const int*)d_in[1];
    const int*   dst   = (const int*)d_in[2];
    const float* Wskip = (const float*)d_in[3];
    const float* bskip = (const float*)d_in[4];
    const float* Wmsg  = (const float*)d_in[5];
    const float* bmsg  = (const float*)d_in[6];

    char* w = (char*)d_ws;

    // Path C layout (split, featsh out-of-place), needs 32,728,320 B:
    //   [0,      400000)   uint pk[N]
    //   [400000, 400128)   int  ovf_cnt (+pad)
    //   [400128, 465664)   ushort Bcat[128*256]
    //   [465664, 466176)   float bias[128]
    //   [466176, 6866176)  int  bucket[N*16]  (zero-initialized)
    //   [6866176,7128320)  int2 ovf[32768]
    //   [7128320,32728320) ushort featsh[N*128]  (256B rows, compact)
    //   aggh lives in d_out rows (first 256B of each 512B row)
    // Path A layout (split, featsh interleaved in d_out), needs 7,128,320 B.
    // Path B layout (count+scan+fill), needs 3,426,688 B.
    bool pathC = ws_size >= (size_t)32728320;
    bool pathA = ws_size >= (size_t)7128320;

    if (pathC) {
        unsigned int*   pk      = (unsigned int*)w;
        int*            ovf_cnt = (int*)(w + 400000);
        unsigned short* Bcat    = (unsigned short*)(w + 400128);
        float*          bias    = (float*)(w + 465664);
        int*            bucket  = (int*)(w + 466176);
        int2*           ovf     = (int2*)(w + 6866176);
        char*           featsh  = w + 7128320;

        // 400000 int4 threads cover bucket[N*16]; pk fits inside that range
        hipLaunchKernelGGL(k_zero, dim3((N_NODES * BKT_C / 4 + 255) / 256),
                           dim3(256), 0, stream, (int4*)pk, (int4*)bucket, ovf_cnt);
        hipLaunchKernelGGL(k_pre, dim3((N_NODES * (D / 8) + 255) / 256), dim3(256),
                           0, stream, feats, Wmsg, Wskip, bmsg, bskip, src, dst, pk,
                           Bcat, bias, featsh, 256, bucket, ovf_cnt, ovf);
        hipLaunchKernelGGL(k_agg_c, dim3((N_NODES * 64 + 255) / 256), dim3(256), 0,
                           stream, (char*)d_out, featsh, pk, bucket, ovf_cnt, ovf);
        hipLaunchKernelGGL(k_gemm_c, dim3((N_NODES + 127) / 128), dim3(256), 0,
                           stream, featsh, Bcat, bias, (float*)d_out);
    } else if (pathA) {
        unsigned int*   pk      = (unsigned int*)w;
        int*            ovf_cnt = (int*)(w + 400000);
        unsigned short* Bcat    = (unsigned short*)(w + 400128);
        float*          bias    = (float*)(w + 465664);
        int*            bucket  = (int*)(w + 466176);
        int2*           ovf     = (int2*)(w + 6866176);

        hipLaunchKernelGGL(k_zero, dim3((N_NODES / 4 + 255) / 256), dim3(256), 0,
                           stream, (int4*)pk, (int4*)nullptr, ovf_cnt);
        hipLaunchKernelGGL(k_pre, dim3((N_NODES * (D / 8) + 255) / 256), dim3(256),
                           0, stream, feats, Wmsg, Wskip, bmsg, bskip, src, dst, pk,
                           Bcat, bias, (char*)d_out + 256, 512, bucket, ovf_cnt, ovf);
        hipLaunchKernelGGL(k_agg_bkt, dim3((N_NODES * 64 + 255) / 256), dim3(256), 0,
                           stream, (char*)d_out, pk, bucket, ovf_cnt, ovf);
        hipLaunchKernelGGL(k_gemm, dim3((N_NODES + 127) / 128), dim3(256), 0, stream,
                           Bcat, bias, (float*)d_out);
    } else {
        unsigned int*   pk      = (unsigned int*)w;
        int*            rowptr  = (int*)(w + 400000);
        int*            bsums   = (int*)(w + 800128);
        unsigned short* Bcat    = (unsigned short*)(w + 800640);
        float*          bias    = (float*)(w + 866176);
        int*            csr_src = (int*)(w + 866688);

        hipLaunchKernelGGL(k_zero, dim3((N_NODES / 4 + 255) / 256), dim3(256), 0,
                           stream, (int4*)pk, (int4*)nullptr, (int*)nullptr);
        hipLaunchKernelGGL(k_pre, dim3((N_NODES * (D / 8) + 255) / 256), dim3(256),
                           0, stream, feats, Wmsg, Wskip, bmsg, bskip, src, dst, pk,
                           Bcat, bias, (char*)d_out + 256, 512, (int*)nullptr,
                           (int*)nullptr, (int2*)nullptr);
        hipLaunchKernelGGL(k_scan1, dim3(NB), dim3(256), 0, stream, pk, rowptr,
                           bsums);
        hipLaunchKernelGGL(k_scan2, dim3(1), dim3(128), 0, stream, bsums);
        hipLaunchKernelGGL(k_scan3, dim3(NB), dim3(256), 0, stream, bsums, rowptr);
        hipLaunchKernelGGL(k_fill, dim3((N_EDGES + 255) / 256), dim3(256), 0, stream,
                           src, dst, rowptr, csr_src);
        hipLaunchKernelGGL(k_agg_csr, dim3((N_NODES * 64 + 255) / 256), dim3(256), 0,
                           stream, (char*)d_out, pk, rowptr, csr_src);
        hipLaunchKernelGGL(k_gemm, dim3((N_NODES + 127) / 128), dim3(256), 0, stream,
                           Bcat, bias, (float*)d_out);
    }
}